// Round 1
// baseline (441.084 us; speedup 1.0000x reference)
//
#include <hip/hip_runtime.h>
#include <stdint.h>

#define T_TOK 4096
#define HID   2048
#define FF    1408
#define NE    8

typedef __attribute__((ext_vector_type(8))) short short8;
typedef __attribute__((ext_vector_type(4))) float f32x4;

__device__ inline unsigned short f2bf(float f) {
  uint32_t u = __builtin_bit_cast(uint32_t, f);
  u += 0x7fffu + ((u >> 16) & 1u);   // RNE
  return (unsigned short)(u >> 16);
}

// ---------------- router: per-token softmax + top2 ----------------
__global__ __launch_bounds__(256) void route_kernel(const float* __restrict__ logits,
                                                    int2* __restrict__ eids,
                                                    float2* __restrict__ ecfs) {
  int t = blockIdx.x * 256 + threadIdx.x;
  const float4* lp = (const float4*)(logits + (size_t)t * NE);
  float4 a = lp[0], b = lp[1];
  float l[8] = {a.x, a.y, a.z, a.w, b.x, b.y, b.z, b.w};
  float mx = l[0];
#pragma unroll
  for (int i = 1; i < 8; ++i) mx = fmaxf(mx, l[i]);
  float s = 0.f, p[8];
#pragma unroll
  for (int i = 0; i < 8; ++i) { p[i] = __expf(l[i] - mx); s += p[i]; }
  float inv = 1.f / s;
  int e0 = 0;
#pragma unroll
  for (int i = 1; i < 8; ++i) if (l[i] > l[e0]) e0 = i;
  int e1 = (e0 == 0) ? 1 : 0;
#pragma unroll
  for (int i = 0; i < 8; ++i) if (i != e0 && l[i] > l[e1]) e1 = i;
  eids[t] = make_int2(e0, e1);
  ecfs[t] = make_float2(p[e0] * inv, p[e1] * inv);
}

// ------------- deterministic per-expert compaction (8 blocks) -------------
__global__ __launch_bounds__(256) void compact_kernel(const int2* __restrict__ eids,
                                                      const float2* __restrict__ ecfs,
                                                      int* __restrict__ tok,
                                                      float* __restrict__ coef,
                                                      int* __restrict__ rowptr) {
  int e = blockIdx.x, tid = threadIdx.x;
  __shared__ int hist[8];
  __shared__ int wsum[4];
  __shared__ int runv;
  if (tid < 8) hist[tid] = 0;
  __syncthreads();
  for (int t = tid; t < T_TOK; t += 256) {
    int2 ei = eids[t];
    atomicAdd(&hist[ei.x], 1);
    atomicAdd(&hist[ei.y], 1);
  }
  __syncthreads();
  int off = 0;
  for (int j = 0; j < e; ++j) off += hist[j];
  if (tid == 0) {
    runv = 0;
    if (e == 0) rowptr[0] = 0;
    rowptr[e + 1] = off + hist[e];
  }
  __syncthreads();
  int wave = tid >> 6, lane = tid & 63;
  for (int c = 0; c < T_TOK; c += 256) {
    int t = c + tid;
    int2 ei = eids[t];
    float2 cf = ecfs[t];
    bool fl = false; float cv = 0.f;
    if (ei.x == e)      { fl = true; cv = cf.x; }
    else if (ei.y == e) { fl = true; cv = cf.y; }
    unsigned long long m = __ballot(fl);
    if (lane == 0) wsum[wave] = __popcll(m);
    __syncthreads();
    int woff = runv;
    for (int wv = 0; wv < wave; ++wv) woff += wsum[wv];
    int pos = off + woff + __popcll(m & ((1ull << lane) - 1ull));
    if (fl) { tok[pos] = t; coef[pos] = cv; }
    __syncthreads();
    if (tid == 0) runv += wsum[0] + wsum[1] + wsum[2] + wsum[3];
    __syncthreads();
  }
}

// ---------------- X f32 -> bf16 ----------------
__global__ __launch_bounds__(256) void cvtx_kernel(const float* __restrict__ x,
                                                   unsigned short* __restrict__ xb) {
  int i = blockIdx.x * 256 + threadIdx.x;  // 4 elems each
  float4 v = ((const float4*)x)[i];
  ushort4 o;
  o.x = f2bf(v.x); o.y = f2bf(v.y); o.z = f2bf(v.z); o.w = f2bf(v.w);
  ((ushort4*)xb)[i] = o;
}

// ---------------- GEMM1: h = silu(X W1g) * (X W1u), gathered rows ----------------
// tile 128M x (64 gate + 64 up), BK=32; 4 waves, wave = 64M x 32F (gate+up accs)
__global__ __launch_bounds__(256) void gemm1_kernel(const unsigned short* __restrict__ Xb,
                                                    const float* __restrict__ w1,
                                                    const int* __restrict__ tok,
                                                    const int* __restrict__ rowptr,
                                                    unsigned short* __restrict__ hbuf) {
  int ftile = blockIdx.x, mtile = blockIdx.y, e = blockIdx.z;
  int base = rowptr[e], cnt = rowptr[e + 1] - base;
  if (mtile * 128 >= cnt) return;
  __shared__ char As[128 * 64];  // [row][32 bf16] 64B rows
  __shared__ char Bs[128 * 64];  // [n][32 bf16] rows, 16B-unit XOR swizzle
  int tid = threadIdx.x, lane = tid & 63, wave = tid >> 6;

  // A staging (reg-staged gather from Xb): units tid (rows 0..63) / tid+256 (64..127)
  int part = tid & 3;
  int s0 = min(mtile * 128 + (tid >> 2), cnt - 1);
  int s1 = min(mtile * 128 + 64 + (tid >> 2), cnt - 1);
  const unsigned short* gA0 = Xb + (size_t)tok[base + s0] * HID + part * 8;
  const unsigned short* gA1 = Xb + (size_t)tok[base + s1] * HID + part * 8;
  char* wA0 = As + tid * 16;
  char* wA1 = As + (256 + tid) * 16;

  // B staging: thread covers LDS rows n2,n2+1 at k kb..kb+7 (transpose in regs)
  int bl = tid & 63, bw = tid >> 6;
  int n2 = bl * 2, kb = bw * 8;
  int gsel = (n2 >= 64) ? 1 : 0;           // gate | up
  int fcol = ftile * 64 + (n2 & 63);
  const float* gB = w1 + ((size_t)(e * 2 + gsel) * HID + kb) * FF + fcol;
  int swz = bl & 3;                         // ((n2>>1)&3) == ((n2+1)>>1)&3
  char* wB0 = Bs + n2 * 64 + ((bw ^ swz) << 4);
  char* wB1 = Bs + (n2 + 1) * 64 + ((bw ^ swz) << 4);

  // fragment read offsets
  int wm = wave >> 1, wf = wave & 1;
  int kc = lane >> 4;
  int aoff[4];
#pragma unroll
  for (int mi = 0; mi < 4; ++mi) {
    int row = wm * 64 + mi * 16 + (lane & 15);
    aoff[mi] = row * 64 + (kc << 4);
  }
  int bgo[2], buo[2];
#pragma unroll
  for (int ni = 0; ni < 2; ++ni) {
    int ng = wf * 32 + ni * 16 + (lane & 15);
    bgo[ni] = ng * 64 + ((kc ^ ((ng >> 1) & 3)) << 4);
    int nu = ng + 64;
    buo[ni] = nu * 64 + ((kc ^ ((nu >> 1) & 3)) << 4);
  }

  const f32x4 vz = {0.f, 0.f, 0.f, 0.f};
  f32x4 accg[4][2], accu[4][2];
#pragma unroll
  for (int mi = 0; mi < 4; ++mi)
#pragma unroll
    for (int ni = 0; ni < 2; ++ni) { accg[mi][ni] = vz; accu[mi][ni] = vz; }

  for (int k0 = 0; k0 < HID; k0 += 32) {
    __syncthreads();
    *(short8*)wA0 = *(const short8*)(gA0 + k0);
    *(short8*)wA1 = *(const short8*)(gA1 + k0);
    const float* gb = gB + (size_t)k0 * FF;
    float2 v[8];
#pragma unroll
    for (int dk = 0; dk < 8; ++dk) v[dk] = *(const float2*)(gb + (size_t)dk * FF);
    short8 px, py;
#pragma unroll
    for (int dk = 0; dk < 8; ++dk) {
      px[dk] = (short)f2bf(v[dk].x);
      py[dk] = (short)f2bf(v[dk].y);
    }
    *(short8*)wB0 = px;
    *(short8*)wB1 = py;
    __syncthreads();
    short8 af[4];
#pragma unroll
    for (int mi = 0; mi < 4; ++mi) af[mi] = *(const short8*)(As + aoff[mi]);
    short8 bg[2], bu[2];
#pragma unroll
    for (int ni = 0; ni < 2; ++ni) {
      bg[ni] = *(const short8*)(Bs + bgo[ni]);
      bu[ni] = *(const short8*)(Bs + buo[ni]);
    }
#pragma unroll
    for (int mi = 0; mi < 4; ++mi)
#pragma unroll
      for (int ni = 0; ni < 2; ++ni) {
        accg[mi][ni] = __builtin_amdgcn_mfma_f32_16x16x32_bf16(af[mi], bg[ni], accg[mi][ni], 0, 0, 0);
        accu[mi][ni] = __builtin_amdgcn_mfma_f32_16x16x32_bf16(af[mi], bu[ni], accu[mi][ni], 0, 0, 0);
      }
  }
  // epilogue: SwiGLU, store h bf16
  int fb = ftile * 64 + wf * 32;
#pragma unroll
  for (int mi = 0; mi < 4; ++mi) {
#pragma unroll
    for (int i = 0; i < 4; ++i) {
      int ml = wm * 64 + mi * 16 + (lane >> 4) * 4 + i;
      int slot = mtile * 128 + ml;
      if (slot < cnt) {
#pragma unroll
        for (int ni = 0; ni < 2; ++ni) {
          float g = accg[mi][ni][i], u = accu[mi][ni][i];
          float hv = g / (1.f + __expf(-g)) * u;
          hbuf[(size_t)(base + slot) * FF + fb + ni * 16 + (lane & 15)] = f2bf(hv);
        }
      }
    }
  }
}

// ---------------- GEMM2: out += coef * (h W2), scatter via atomics ----------------
// tile 128M x 128N, BK=32; wave = 64x64
__global__ __launch_bounds__(256) void gemm2_kernel(const unsigned short* __restrict__ hbuf,
                                                    const float* __restrict__ w2,
                                                    const int* __restrict__ tok,
                                                    const float* __restrict__ coef,
                                                    const int* __restrict__ rowptr,
                                                    float* __restrict__ out) {
  int ntile = blockIdx.x, mtile = blockIdx.y, e = blockIdx.z;
  int base = rowptr[e], cnt = rowptr[e + 1] - base;
  if (mtile * 128 >= cnt) return;
  __shared__ char As[128 * 64];
  __shared__ char Bs[128 * 64];
  __shared__ int tokL[128];
  __shared__ float cofL[128];
  int tid = threadIdx.x, lane = tid & 63, wave = tid >> 6;
  if (tid < 128) {
    int slot = min(mtile * 128 + tid, cnt - 1);
    tokL[tid] = tok[base + slot];
    cofL[tid] = coef[base + slot];
  }
  int part = tid & 3;
  int s0 = min(mtile * 128 + (tid >> 2), cnt - 1);
  int s1 = min(mtile * 128 + 64 + (tid >> 2), cnt - 1);
  const unsigned short* gA0 = hbuf + (size_t)(base + s0) * FF + part * 8;
  const unsigned short* gA1 = hbuf + (size_t)(base + s1) * FF + part * 8;
  char* wA0 = As + tid * 16;
  char* wA1 = As + (256 + tid) * 16;

  int bl = tid & 63, bw = tid >> 6;
  int n2 = bl * 2, kb = bw * 8;
  int ncol = ntile * 128 + n2;
  const float* gB = w2 + ((size_t)e * FF + kb) * HID + ncol;
  int swz = bl & 3;
  char* wB0 = Bs + n2 * 64 + ((bw ^ swz) << 4);
  char* wB1 = Bs + (n2 + 1) * 64 + ((bw ^ swz) << 4);

  int wm = wave >> 1, wn = wave & 1;
  int kc = lane >> 4;
  int aoff[4], bo[4];
#pragma unroll
  for (int mi = 0; mi < 4; ++mi) {
    int row = wm * 64 + mi * 16 + (lane & 15);
    aoff[mi] = row * 64 + (kc << 4);
  }
#pragma unroll
  for (int ni = 0; ni < 4; ++ni) {
    int n = wn * 64 + ni * 16 + (lane & 15);
    bo[ni] = n * 64 + ((kc ^ ((n >> 1) & 3)) << 4);
  }

  const f32x4 vz = {0.f, 0.f, 0.f, 0.f};
  f32x4 acc[4][4];
#pragma unroll
  for (int mi = 0; mi < 4; ++mi)
#pragma unroll
    for (int ni = 0; ni < 4; ++ni) acc[mi][ni] = vz;

  for (int k0 = 0; k0 < FF; k0 += 32) {
    __syncthreads();
    *(short8*)wA0 = *(const short8*)(gA0 + k0);
    *(short8*)wA1 = *(const short8*)(gA1 + k0);
    const float* gb = gB + (size_t)k0 * HID;
    float2 v[8];
#pragma unroll
    for (int dk = 0; dk < 8; ++dk) v[dk] = *(const float2*)(gb + (size_t)dk * HID);
    short8 px, py;
#pragma unroll
    for (int dk = 0; dk < 8; ++dk) {
      px[dk] = (short)f2bf(v[dk].x);
      py[dk] = (short)f2bf(v[dk].y);
    }
    *(short8*)wB0 = px;
    *(short8*)wB1 = py;
    __syncthreads();
    short8 af[4], bb[4];
#pragma unroll
    for (int mi = 0; mi < 4; ++mi) af[mi] = *(const short8*)(As + aoff[mi]);
#pragma unroll
    for (int ni = 0; ni < 4; ++ni) bb[ni] = *(const short8*)(Bs + bo[ni]);
#pragma unroll
    for (int mi = 0; mi < 4; ++mi)
#pragma unroll
      for (int ni = 0; ni < 4; ++ni)
        acc[mi][ni] = __builtin_amdgcn_mfma_f32_16x16x32_bf16(af[mi], bb[ni], acc[mi][ni], 0, 0, 0);
  }
#pragma unroll
  for (int mi = 0; mi < 4; ++mi) {
#pragma unroll
    for (int i = 0; i < 4; ++i) {
      int ml = wm * 64 + mi * 16 + (lane >> 4) * 4 + i;
      int slot = mtile * 128 + ml;
      if (slot < cnt) {
        float cf = cofL[ml];
        float* op = out + (size_t)tokL[ml] * HID + ntile * 128 + wn * 64 + (lane & 15);
#pragma unroll
        for (int ni = 0; ni < 4; ++ni)
          unsafeAtomicAdd(op + ni * 16, cf * acc[mi][ni][i]);
      }
    }
  }
}

extern "C" void kernel_launch(void* const* d_in, const int* in_sizes, int n_in,
                              void* d_out, int out_size, void* d_ws, size_t ws_size,
                              hipStream_t stream) {
  const float* X  = (const float*)d_in[0];
  const float* RL = (const float*)d_in[1];
  const float* W1 = (const float*)d_in[2];
  const float* W2 = (const float*)d_in[3];
  float* out = (float*)d_out;

  const size_t OFF_EIDS = 4096;
  const size_t OFF_ECFS = 36864;
  const size_t OFF_TOK  = 69632;
  const size_t OFF_COEF = 102400;
  const size_t OFF_XB   = 135168;
  const size_t OFF_H    = 16912384;
  const size_t TOTAL    = 39981056;
  if (ws_size < TOTAL || n_in < 4) return;  // ws too small: leaves zeros (diagnostic)

  char* w = (char*)d_ws;
  int*    rowptr = (int*)w;
  int2*   eids   = (int2*)(w + OFF_EIDS);
  float2* ecfs   = (float2*)(w + OFF_ECFS);
  int*    tok    = (int*)(w + OFF_TOK);
  float*  coef   = (float*)(w + OFF_COEF);
  unsigned short* Xb   = (unsigned short*)(w + OFF_XB);
  unsigned short* hbuf = (unsigned short*)(w + OFF_H);

  hipMemsetAsync(d_out, 0, (size_t)T_TOK * HID * sizeof(float), stream);
  route_kernel<<<T_TOK / 256, 256, 0, stream>>>(RL, eids, ecfs);
  compact_kernel<<<NE, 256, 0, stream>>>(eids, ecfs, tok, coef, rowptr);
  cvtx_kernel<<<(T_TOK * HID / 4) / 256, 256, 0, stream>>>(X, Xb);
  gemm1_kernel<<<dim3(FF / 64, T_TOK / 128, NE), 256, 0, stream>>>(Xb, W1, tok, rowptr, hbuf);
  gemm2_kernel<<<dim3(HID / 128, T_TOK / 128, NE), 256, 0, stream>>>(hbuf, W2, tok, coef, rowptr, out);
}

// Round 2
// 415.898 us; speedup vs baseline: 1.0606x; 1.0606x over previous
//
#include <hip/hip_runtime.h>
#include <stdint.h>

#define T_TOK 4096
#define HID   2048
#define FF    1408
#define NE    8

typedef __attribute__((ext_vector_type(8))) short short8;
typedef __attribute__((ext_vector_type(4))) float f32x4;
typedef __attribute__((ext_vector_type(4))) unsigned int u32x4;

__device__ inline unsigned short f2bf(float f) {
  uint32_t u = __builtin_bit_cast(uint32_t, f);
  u += 0x7fffu + ((u >> 16) & 1u);   // RNE
  return (unsigned short)(u >> 16);
}

// hardware packed f32x2 -> bf16x2 (1 VALU op; replaces ~12 ops of manual cvt+pack)
__device__ inline uint32_t cvt_pk(float a, float b) {
  uint32_t r;
  asm("v_cvt_pk_bf16_f32 %0, %1, %2" : "=v"(r) : "v"(a), "v"(b));
  return r;
}

// raw barrier pair: no compiler vmcnt(0) drain -> prefetch loads stay in flight
__device__ inline void bar_top() {
  asm volatile("" ::: "memory");
  __builtin_amdgcn_s_barrier();
  asm volatile("" ::: "memory");
}
__device__ inline void bar_lds_ready() {
  asm volatile("s_waitcnt lgkmcnt(0)" ::: "memory");
  __builtin_amdgcn_s_barrier();
  asm volatile("" ::: "memory");
}

// ---------------- router: per-token softmax + top2 ----------------
__global__ __launch_bounds__(256) void route_kernel(const float* __restrict__ logits,
                                                    int2* __restrict__ eids,
                                                    float2* __restrict__ ecfs) {
  int t = blockIdx.x * 256 + threadIdx.x;
  const float4* lp = (const float4*)(logits + (size_t)t * NE);
  float4 a = lp[0], b = lp[1];
  float l[8] = {a.x, a.y, a.z, a.w, b.x, b.y, b.z, b.w};
  float mx = l[0];
#pragma unroll
  for (int i = 1; i < 8; ++i) mx = fmaxf(mx, l[i]);
  float s = 0.f, p[8];
#pragma unroll
  for (int i = 0; i < 8; ++i) { p[i] = __expf(l[i] - mx); s += p[i]; }
  float inv = 1.f / s;
  int e0 = 0;
#pragma unroll
  for (int i = 1; i < 8; ++i) if (l[i] > l[e0]) e0 = i;
  int e1 = (e0 == 0) ? 1 : 0;
#pragma unroll
  for (int i = 0; i < 8; ++i) if (i != e0 && l[i] > l[e1]) e1 = i;
  eids[t] = make_int2(e0, e1);
  ecfs[t] = make_float2(p[e0] * inv, p[e1] * inv);
}

// ------------- deterministic per-expert compaction (8 blocks) -------------
__global__ __launch_bounds__(256) void compact_kernel(const int2* __restrict__ eids,
                                                      const float2* __restrict__ ecfs,
                                                      int* __restrict__ tok,
                                                      float* __restrict__ coef,
                                                      int* __restrict__ rowptr) {
  int e = blockIdx.x, tid = threadIdx.x;
  __shared__ int hist[8];
  __shared__ int wsum[4];
  __shared__ int runv;
  if (tid < 8) hist[tid] = 0;
  __syncthreads();
  for (int t = tid; t < T_TOK; t += 256) {
    int2 ei = eids[t];
    atomicAdd(&hist[ei.x], 1);
    atomicAdd(&hist[ei.y], 1);
  }
  __syncthreads();
  int off = 0;
  for (int j = 0; j < e; ++j) off += hist[j];
  if (tid == 0) {
    runv = 0;
    if (e == 0) rowptr[0] = 0;
    rowptr[e + 1] = off + hist[e];
  }
  __syncthreads();
  int wave = tid >> 6, lane = tid & 63;
  for (int c = 0; c < T_TOK; c += 256) {
    int t = c + tid;
    int2 ei = eids[t];
    float2 cf = ecfs[t];
    bool fl = false; float cv = 0.f;
    if (ei.x == e)      { fl = true; cv = cf.x; }
    else if (ei.y == e) { fl = true; cv = cf.y; }
    unsigned long long m = __ballot(fl);
    if (lane == 0) wsum[wave] = __popcll(m);
    __syncthreads();
    int woff = runv;
    for (int wv = 0; wv < wave; ++wv) woff += wsum[wv];
    int pos = off + woff + __popcll(m & ((1ull << lane) - 1ull));
    if (fl) { tok[pos] = t; coef[pos] = cv; }
    __syncthreads();
    if (tid == 0) runv += wsum[0] + wsum[1] + wsum[2] + wsum[3];
    __syncthreads();
  }
}

// ---------------- X f32 -> bf16 ----------------
__global__ __launch_bounds__(256) void cvtx_kernel(const float* __restrict__ x,
                                                   unsigned short* __restrict__ xb) {
  int i = blockIdx.x * 256 + threadIdx.x;  // 4 elems each
  float4 v = ((const float4*)x)[i];
  uint2 o;
  o.x = cvt_pk(v.x, v.y);
  o.y = cvt_pk(v.z, v.w);
  ((uint2*)xb)[i] = o;
}

// ---------------- GEMM1: h = silu(X W1g) * (X W1u), gathered rows ----------------
// tile 128M x (64 gate + 64 up), BK=32; 4 waves, wave = 64M x 32F (gate+up accs)
// LDS: As/Bs [row][64B], 16B chunks XOR-swizzled by ((row>>1)&3) -> reads at bank floor
__global__ __launch_bounds__(256) void gemm1_kernel(const unsigned short* __restrict__ Xb,
                                                    const float* __restrict__ w1,
                                                    const int* __restrict__ tok,
                                                    const int* __restrict__ rowptr,
                                                    unsigned short* __restrict__ hbuf) {
  int ftile = blockIdx.x, mtile = blockIdx.y, e = blockIdx.z;
  int base = rowptr[e], cnt = rowptr[e + 1] - base;
  if (mtile * 128 >= cnt) return;
  __shared__ char As[128 * 64];
  __shared__ char Bs[128 * 64];
  int tid = threadIdx.x, lane = tid & 63, wave = tid >> 6;

  // A staging: thread owns rows r0, r0+64 at 16B chunk c (8 bf16 k's)
  int c = tid & 3, r0 = tid >> 2;
  int s0 = min(mtile * 128 + r0, cnt - 1);
  int s1 = min(mtile * 128 + 64 + r0, cnt - 1);
  const unsigned short* gA0 = Xb + (size_t)tok[base + s0] * HID + c * 8;
  const unsigned short* gA1 = Xb + (size_t)tok[base + s1] * HID + c * 8;
  int swzA = c ^ ((r0 >> 1) & 3);              // (r0+64)>>1 & 3 identical
  char* wA0 = As + r0 * 64 + (swzA << 4);
  char* wA1 = As + (64 + r0) * 64 + (swzA << 4);

  // B staging: thread owns rows n2, n2+1 (f cols), k-chunk bw (8 k's); reg transpose
  int bl = tid & 63, bw = tid >> 6;
  int n2 = bl * 2;
  int gsel = (n2 >= 64) ? 1 : 0;               // gate | up
  int fcol = ftile * 64 + (n2 & 63);
  const float* gB = w1 + ((size_t)(e * 2 + gsel) * HID + bw * 8) * FF + fcol;
  int swzB = bw ^ ((n2 >> 1) & 3);             // same for n2+1
  char* wB0 = Bs + n2 * 64 + (swzB << 4);
  char* wB1 = Bs + (n2 + 1) * 64 + (swzB << 4);

  // fragment read offsets (swizzled)
  int wm = wave >> 1, wf = wave & 1;
  int kc = lane >> 4;
  int aoff[4];
#pragma unroll
  for (int mi = 0; mi < 4; ++mi) {
    int row = wm * 64 + mi * 16 + (lane & 15);
    aoff[mi] = row * 64 + ((kc ^ ((row >> 1) & 3)) << 4);
  }
  int bgo[2];
#pragma unroll
  for (int ni = 0; ni < 2; ++ni) {
    int ng = wf * 32 + ni * 16 + (lane & 15);
    bgo[ni] = ng * 64 + ((kc ^ ((ng >> 1) & 3)) << 4);   // up frag = bgo + 64*64
  }

  const f32x4 vz = {0.f, 0.f, 0.f, 0.f};
  f32x4 accg[4][2], accu[4][2];
#pragma unroll
  for (int mi = 0; mi < 4; ++mi)
#pragma unroll
    for (int ni = 0; ni < 2; ++ni) { accg[mi][ni] = vz; accu[mi][ni] = vz; }

  // prologue: load k-chunk 0 into regs
  short8 a0 = *(const short8*)gA0;
  short8 a1 = *(const short8*)gA1;
  float2 v[8];
#pragma unroll
  for (int dk = 0; dk < 8; ++dk) v[dk] = *(const float2*)(gB + (size_t)dk * FF);

  for (int k0 = 0; k0 < HID; k0 += 32) {
    int kn = (k0 + 32 < HID) ? k0 + 32 : k0;   // last iter: dummy refetch
    bar_top();                                  // all waves done reading LDS
    u32x4 px, py;
#pragma unroll
    for (int j = 0; j < 4; ++j) {
      px[j] = cvt_pk(v[2 * j].x, v[2 * j + 1].x);
      py[j] = cvt_pk(v[2 * j].y, v[2 * j + 1].y);
    }
    *(short8*)wA0 = a0;
    *(short8*)wA1 = a1;
    *(u32x4*)wB0 = px;
    *(u32x4*)wB1 = py;
    // prefetch next chunk (consumed after next bar_top -> latency hidden)
    a0 = *(const short8*)(gA0 + kn);
    a1 = *(const short8*)(gA1 + kn);
#pragma unroll
    for (int dk = 0; dk < 8; ++dk) v[dk] = *(const float2*)(gB + ((size_t)kn + dk) * FF);
    bar_lds_ready();                            // lgkmcnt(0) + barrier (no vmcnt drain)
    short8 af[4];
#pragma unroll
    for (int mi = 0; mi < 4; ++mi) af[mi] = *(const short8*)(As + aoff[mi]);
    short8 bg[2], bu[2];
#pragma unroll
    for (int ni = 0; ni < 2; ++ni) {
      bg[ni] = *(const short8*)(Bs + bgo[ni]);
      bu[ni] = *(const short8*)(Bs + bgo[ni] + 64 * 64);
    }
#pragma unroll
    for (int mi = 0; mi < 4; ++mi)
#pragma unroll
      for (int ni = 0; ni < 2; ++ni) {
        accg[mi][ni] = __builtin_amdgcn_mfma_f32_16x16x32_bf16(af[mi], bg[ni], accg[mi][ni], 0, 0, 0);
        accu[mi][ni] = __builtin_amdgcn_mfma_f32_16x16x32_bf16(af[mi], bu[ni], accu[mi][ni], 0, 0, 0);
      }
  }
  // epilogue: SwiGLU, store h bf16
  int fb = ftile * 64 + wf * 32;
#pragma unroll
  for (int mi = 0; mi < 4; ++mi) {
#pragma unroll
    for (int i = 0; i < 4; ++i) {
      int ml = wm * 64 + mi * 16 + (lane >> 4) * 4 + i;
      int slot = mtile * 128 + ml;
      if (slot < cnt) {
#pragma unroll
        for (int ni = 0; ni < 2; ++ni) {
          float g = accg[mi][ni][i], u = accu[mi][ni][i];
          float hv = g / (1.f + __expf(-g)) * u;
          hbuf[(size_t)(base + slot) * FF + fb + ni * 16 + (lane & 15)] = f2bf(hv);
        }
      }
    }
  }
}

// ---------------- GEMM2: out += coef * (h W2), scatter via atomics ----------------
// tile 128M x 128N, BK=32; wave = 64x64
__global__ __launch_bounds__(256) void gemm2_kernel(const unsigned short* __restrict__ hbuf,
                                                    const float* __restrict__ w2,
                                                    const int* __restrict__ tok,
                                                    const float* __restrict__ coef,
                                                    const int* __restrict__ rowptr,
                                                    float* __restrict__ out) {
  int ntile = blockIdx.x, mtile = blockIdx.y, e = blockIdx.z;
  int base = rowptr[e], cnt = rowptr[e + 1] - base;
  if (mtile * 128 >= cnt) return;
  __shared__ char As[128 * 64];
  __shared__ char Bs[128 * 64];
  __shared__ int tokL[128];
  __shared__ float cofL[128];
  int tid = threadIdx.x, lane = tid & 63, wave = tid >> 6;
  if (tid < 128) {
    int slot = min(mtile * 128 + tid, cnt - 1);
    tokL[tid] = tok[base + slot];
    cofL[tid] = coef[base + slot];
  }
  __syncthreads();   // tokL/cofL ready before any raw-barrier traffic

  int c = tid & 3, r0 = tid >> 2;
  int s0 = min(mtile * 128 + r0, cnt - 1);
  int s1 = min(mtile * 128 + 64 + r0, cnt - 1);
  const unsigned short* gA0 = hbuf + (size_t)(base + s0) * FF + c * 8;
  const unsigned short* gA1 = hbuf + (size_t)(base + s1) * FF + c * 8;
  int swzA = c ^ ((r0 >> 1) & 3);
  char* wA0 = As + r0 * 64 + (swzA << 4);
  char* wA1 = As + (64 + r0) * 64 + (swzA << 4);

  int bl = tid & 63, bw = tid >> 6;
  int n2 = bl * 2;
  int ncol = ntile * 128 + n2;
  const float* gB = w2 + ((size_t)e * FF + bw * 8) * HID + ncol;
  int swzB = bw ^ ((n2 >> 1) & 3);
  char* wB0 = Bs + n2 * 64 + (swzB << 4);
  char* wB1 = Bs + (n2 + 1) * 64 + (swzB << 4);

  int wm = wave >> 1, wn = wave & 1;
  int kc = lane >> 4;
  int aoff[4], bo[4];
#pragma unroll
  for (int mi = 0; mi < 4; ++mi) {
    int row = wm * 64 + mi * 16 + (lane & 15);
    aoff[mi] = row * 64 + ((kc ^ ((row >> 1) & 3)) << 4);
  }
#pragma unroll
  for (int ni = 0; ni < 4; ++ni) {
    int n = wn * 64 + ni * 16 + (lane & 15);
    bo[ni] = n * 64 + ((kc ^ ((n >> 1) & 3)) << 4);
  }

  const f32x4 vz = {0.f, 0.f, 0.f, 0.f};
  f32x4 acc[4][4];
#pragma unroll
  for (int mi = 0; mi < 4; ++mi)
#pragma unroll
    for (int ni = 0; ni < 4; ++ni) acc[mi][ni] = vz;

  short8 a0 = *(const short8*)gA0;
  short8 a1 = *(const short8*)gA1;
  float2 v[8];
#pragma unroll
  for (int dk = 0; dk < 8; ++dk) v[dk] = *(const float2*)(gB + (size_t)dk * HID);

  for (int k0 = 0; k0 < FF; k0 += 32) {
    int kn = (k0 + 32 < FF) ? k0 + 32 : k0;
    bar_top();
    u32x4 px, py;
#pragma unroll
    for (int j = 0; j < 4; ++j) {
      px[j] = cvt_pk(v[2 * j].x, v[2 * j + 1].x);
      py[j] = cvt_pk(v[2 * j].y, v[2 * j + 1].y);
    }
    *(short8*)wA0 = a0;
    *(short8*)wA1 = a1;
    *(u32x4*)wB0 = px;
    *(u32x4*)wB1 = py;
    a0 = *(const short8*)(gA0 + kn);
    a1 = *(const short8*)(gA1 + kn);
#pragma unroll
    for (int dk = 0; dk < 8; ++dk) v[dk] = *(const float2*)(gB + ((size_t)kn + dk) * HID);
    bar_lds_ready();
    short8 af[4], bb[4];
#pragma unroll
    for (int mi = 0; mi < 4; ++mi) af[mi] = *(const short8*)(As + aoff[mi]);
#pragma unroll
    for (int ni = 0; ni < 4; ++ni) bb[ni] = *(const short8*)(Bs + bo[ni]);
#pragma unroll
    for (int mi = 0; mi < 4; ++mi)
#pragma unroll
      for (int ni = 0; ni < 4; ++ni)
        acc[mi][ni] = __builtin_amdgcn_mfma_f32_16x16x32_bf16(af[mi], bb[ni], acc[mi][ni], 0, 0, 0);
  }
#pragma unroll
  for (int mi = 0; mi < 4; ++mi) {
#pragma unroll
    for (int i = 0; i < 4; ++i) {
      int ml = wm * 64 + mi * 16 + (lane >> 4) * 4 + i;
      int slot = mtile * 128 + ml;
      if (slot < cnt) {
        float cf = cofL[ml];
        float* op = out + (size_t)tokL[ml] * HID + ntile * 128 + wn * 64 + (lane & 15);
#pragma unroll
        for (int ni = 0; ni < 4; ++ni)
          unsafeAtomicAdd(op + ni * 16, cf * acc[mi][ni][i]);
      }
    }
  }
}

extern "C" void kernel_launch(void* const* d_in, const int* in_sizes, int n_in,
                              void* d_out, int out_size, void* d_ws, size_t ws_size,
                              hipStream_t stream) {
  const float* X  = (const float*)d_in[0];
  const float* RL = (const float*)d_in[1];
  const float* W1 = (const float*)d_in[2];
  const float* W2 = (const float*)d_in[3];
  float* out = (float*)d_out;

  const size_t OFF_EIDS = 4096;
  const size_t OFF_ECFS = 36864;
  const size_t OFF_TOK  = 69632;
  const size_t OFF_COEF = 102400;
  const size_t OFF_XB   = 135168;
  const size_t OFF_H    = 16912384;
  const size_t TOTAL    = 39981056;
  if (ws_size < TOTAL || n_in < 4) return;

  char* w = (char*)d_ws;
  int*    rowptr = (int*)w;
  int2*   eids   = (int2*)(w + OFF_EIDS);
  float2* ecfs   = (float2*)(w + OFF_ECFS);
  int*    tok    = (int*)(w + OFF_TOK);
  float*  coef   = (float*)(w + OFF_COEF);
  unsigned short* Xb   = (unsigned short*)(w + OFF_XB);
  unsigned short* hbuf = (unsigned short*)(w + OFF_H);

  hipMemsetAsync(d_out, 0, (size_t)T_TOK * HID * sizeof(float), stream);
  route_kernel<<<T_TOK / 256, 256, 0, stream>>>(RL, eids, ecfs);
  compact_kernel<<<NE, 256, 0, stream>>>(eids, ecfs, tok, coef, rowptr);
  cvtx_kernel<<<(T_TOK * HID / 4) / 256, 256, 0, stream>>>(X, Xb);
  gemm1_kernel<<<dim3(FF / 64, T_TOK / 128, NE), 256, 0, stream>>>(Xb, W1, tok, rowptr, hbuf);
  gemm2_kernel<<<dim3(HID / 128, T_TOK / 128, NE), 256, 0, stream>>>(hbuf, W2, tok, coef, rowptr, out);
}

// Round 3
// 409.529 us; speedup vs baseline: 1.0771x; 1.0156x over previous
//
#include <hip/hip_runtime.h>
#include <stdint.h>

#define T_TOK 4096
#define HID   2048
#define FF    1408
#define NE    8

typedef __attribute__((ext_vector_type(8))) short short8;
typedef __attribute__((ext_vector_type(4))) float f32x4;
typedef __attribute__((ext_vector_type(4))) unsigned int u32x4;

__device__ inline unsigned short f2bf(float f) {
  uint32_t u = __builtin_bit_cast(uint32_t, f);
  u += 0x7fffu + ((u >> 16) & 1u);   // RNE
  return (unsigned short)(u >> 16);
}

// hardware packed f32x2 -> bf16x2 (1 VALU op)
__device__ inline uint32_t cvt_pk(float a, float b) {
  uint32_t r;
  asm("v_cvt_pk_bf16_f32 %0, %1, %2" : "=v"(r) : "v"(a), "v"(b));
  return r;
}

// raw barrier pair: no compiler vmcnt(0) drain -> prefetch loads stay in flight
__device__ inline void bar_top() {
  asm volatile("" ::: "memory");
  __builtin_amdgcn_s_barrier();
  asm volatile("" ::: "memory");
}
__device__ inline void bar_lds_ready() {
  asm volatile("s_waitcnt lgkmcnt(0)" ::: "memory");
  __builtin_amdgcn_s_barrier();
  asm volatile("" ::: "memory");
}

// ---------------- router: per-token softmax + top2 ----------------
__global__ __launch_bounds__(256) void route_kernel(const float* __restrict__ logits,
                                                    int2* __restrict__ eids,
                                                    float2* __restrict__ ecfs) {
  int t = blockIdx.x * 256 + threadIdx.x;
  const float4* lp = (const float4*)(logits + (size_t)t * NE);
  float4 a = lp[0], b = lp[1];
  float l[8] = {a.x, a.y, a.z, a.w, b.x, b.y, b.z, b.w};
  float mx = l[0];
#pragma unroll
  for (int i = 1; i < 8; ++i) mx = fmaxf(mx, l[i]);
  float s = 0.f, p[8];
#pragma unroll
  for (int i = 0; i < 8; ++i) { p[i] = __expf(l[i] - mx); s += p[i]; }
  float inv = 1.f / s;
  int e0 = 0;
#pragma unroll
  for (int i = 1; i < 8; ++i) if (l[i] > l[e0]) e0 = i;
  int e1 = (e0 == 0) ? 1 : 0;
#pragma unroll
  for (int i = 0; i < 8; ++i) if (i != e0 && l[i] > l[e1]) e1 = i;
  eids[t] = make_int2(e0, e1);
  ecfs[t] = make_float2(p[e0] * inv, p[e1] * inv);
}

// ------------- deterministic per-expert compaction (8 blocks) -------------
__global__ __launch_bounds__(256) void compact_kernel(const int2* __restrict__ eids,
                                                      const float2* __restrict__ ecfs,
                                                      int* __restrict__ tok,
                                                      float* __restrict__ coef,
                                                      int* __restrict__ rowptr) {
  int e = blockIdx.x, tid = threadIdx.x;
  __shared__ int hist[8];
  __shared__ int wsum[4];
  __shared__ int runv;
  if (tid < 8) hist[tid] = 0;
  __syncthreads();
  for (int t = tid; t < T_TOK; t += 256) {
    int2 ei = eids[t];
    atomicAdd(&hist[ei.x], 1);
    atomicAdd(&hist[ei.y], 1);
  }
  __syncthreads();
  int off = 0;
  for (int j = 0; j < e; ++j) off += hist[j];
  if (tid == 0) {
    runv = 0;
    if (e == 0) rowptr[0] = 0;
    rowptr[e + 1] = off + hist[e];
  }
  __syncthreads();
  int wave = tid >> 6, lane = tid & 63;
  for (int c = 0; c < T_TOK; c += 256) {
    int t = c + tid;
    int2 ei = eids[t];
    float2 cf = ecfs[t];
    bool fl = false; float cv = 0.f;
    if (ei.x == e)      { fl = true; cv = cf.x; }
    else if (ei.y == e) { fl = true; cv = cf.y; }
    unsigned long long m = __ballot(fl);
    if (lane == 0) wsum[wave] = __popcll(m);
    __syncthreads();
    int woff = runv;
    for (int wv = 0; wv < wave; ++wv) woff += wsum[wv];
    int pos = off + woff + __popcll(m & ((1ull << lane) - 1ull));
    if (fl) { tok[pos] = t; coef[pos] = cv; }
    __syncthreads();
    if (tid == 0) runv += wsum[0] + wsum[1] + wsum[2] + wsum[3];
    __syncthreads();
  }
}

// ---------------- X f32 -> bf16 ----------------
__global__ __launch_bounds__(256) void cvtx_kernel(const float* __restrict__ x,
                                                   unsigned short* __restrict__ xb) {
  int i = blockIdx.x * 256 + threadIdx.x;  // 4 elems each
  float4 v = ((const float4*)x)[i];
  uint2 o;
  o.x = cvt_pk(v.x, v.y);
  o.y = cvt_pk(v.z, v.w);
  ((uint2*)xb)[i] = o;
}

// ---------------- GEMM1: h = silu(X W1g) * (X W1u), gathered rows ----------------
// tile 128M x (64 gate + 64 up), BK=32; 4 waves, wave = 64M x 32F (gate+up accs)
// LDS: As/Bs [row][64B], 16B chunks XOR-swizzled by ((row>>1)&3) -> reads at bank floor
// Work-remap: all 32 mtiles of one ftile are consecutive blocks -> same XCD,
// B panel (1 MB) becomes L2-resident instead of 8x re-fetched from HBM.
__global__ __launch_bounds__(256) void gemm1_kernel(const unsigned short* __restrict__ Xb,
                                                    const float* __restrict__ w1,
                                                    const int* __restrict__ tok,
                                                    const int* __restrict__ rowptr,
                                                    unsigned short* __restrict__ hbuf) {
  // XCD-chunked bijective remap: 704 blocks/expert, 88 per XCD (704 % 8 == 0)
  int f = blockIdx.x + 22 * blockIdx.y;
  int g = (f & 7) * 88 + (f >> 3);
  int ftile = g >> 5, mtile = g & 31;
  int e = blockIdx.z;
  int base = rowptr[e], cnt = rowptr[e + 1] - base;
  if (mtile * 128 >= cnt) return;
  __shared__ char As[128 * 64];
  __shared__ char Bs[128 * 64];
  int tid = threadIdx.x, lane = tid & 63, wave = tid >> 6;

  // A staging: thread owns rows r0, r0+64 at 16B chunk c (8 bf16 k's)
  int c = tid & 3, r0 = tid >> 2;
  int s0 = min(mtile * 128 + r0, cnt - 1);
  int s1 = min(mtile * 128 + 64 + r0, cnt - 1);
  const unsigned short* gA0 = Xb + (size_t)tok[base + s0] * HID + c * 8;
  const unsigned short* gA1 = Xb + (size_t)tok[base + s1] * HID + c * 8;
  int swzA = c ^ ((r0 >> 1) & 3);              // (r0+64)>>1 & 3 identical
  char* wA0 = As + r0 * 64 + (swzA << 4);
  char* wA1 = As + (64 + r0) * 64 + (swzA << 4);

  // B staging: thread owns rows n2, n2+1 (f cols), k-chunk bw (8 k's); reg transpose
  int bl = tid & 63, bw = tid >> 6;
  int n2 = bl * 2;
  int gsel = (n2 >= 64) ? 1 : 0;               // gate | up
  int fcol = ftile * 64 + (n2 & 63);
  const float* gB = w1 + ((size_t)(e * 2 + gsel) * HID + bw * 8) * FF + fcol;
  int swzB = bw ^ ((n2 >> 1) & 3);             // same for n2+1
  char* wB0 = Bs + n2 * 64 + (swzB << 4);
  char* wB1 = Bs + (n2 + 1) * 64 + (swzB << 4);

  // fragment read offsets (swizzled)
  int wm = wave >> 1, wf = wave & 1;
  int kc = lane >> 4;
  int aoff[4];
#pragma unroll
  for (int mi = 0; mi < 4; ++mi) {
    int row = wm * 64 + mi * 16 + (lane & 15);
    aoff[mi] = row * 64 + ((kc ^ ((row >> 1) & 3)) << 4);
  }
  int bgo[2];
#pragma unroll
  for (int ni = 0; ni < 2; ++ni) {
    int ng = wf * 32 + ni * 16 + (lane & 15);
    bgo[ni] = ng * 64 + ((kc ^ ((ng >> 1) & 3)) << 4);   // up frag = bgo + 64*64
  }

  const f32x4 vz = {0.f, 0.f, 0.f, 0.f};
  f32x4 accg[4][2], accu[4][2];
#pragma unroll
  for (int mi = 0; mi < 4; ++mi)
#pragma unroll
    for (int ni = 0; ni < 2; ++ni) { accg[mi][ni] = vz; accu[mi][ni] = vz; }

  // prologue: load k-chunk 0 into regs
  short8 a0 = *(const short8*)gA0;
  short8 a1 = *(const short8*)gA1;
  float2 v[8];
#pragma unroll
  for (int dk = 0; dk < 8; ++dk) v[dk] = *(const float2*)(gB + (size_t)dk * FF);

  for (int k0 = 0; k0 < HID; k0 += 32) {
    int kn = (k0 + 32 < HID) ? k0 + 32 : k0;   // last iter: dummy refetch
    bar_top();                                  // all waves done reading LDS
    u32x4 px, py;
#pragma unroll
    for (int j = 0; j < 4; ++j) {
      px[j] = cvt_pk(v[2 * j].x, v[2 * j + 1].x);
      py[j] = cvt_pk(v[2 * j].y, v[2 * j + 1].y);
    }
    *(short8*)wA0 = a0;
    *(short8*)wA1 = a1;
    *(u32x4*)wB0 = px;
    *(u32x4*)wB1 = py;
    // prefetch next chunk (consumed after next bar_top -> latency hidden)
    a0 = *(const short8*)(gA0 + kn);
    a1 = *(const short8*)(gA1 + kn);
#pragma unroll
    for (int dk = 0; dk < 8; ++dk) v[dk] = *(const float2*)(gB + ((size_t)kn + dk) * FF);
    bar_lds_ready();                            // lgkmcnt(0) + barrier (no vmcnt drain)
    short8 af[4];
#pragma unroll
    for (int mi = 0; mi < 4; ++mi) af[mi] = *(const short8*)(As + aoff[mi]);
    short8 bg[2], bu[2];
#pragma unroll
    for (int ni = 0; ni < 2; ++ni) {
      bg[ni] = *(const short8*)(Bs + bgo[ni]);
      bu[ni] = *(const short8*)(Bs + bgo[ni] + 64 * 64);
    }
#pragma unroll
    for (int mi = 0; mi < 4; ++mi)
#pragma unroll
      for (int ni = 0; ni < 2; ++ni) {
        accg[mi][ni] = __builtin_amdgcn_mfma_f32_16x16x32_bf16(af[mi], bg[ni], accg[mi][ni], 0, 0, 0);
        accu[mi][ni] = __builtin_amdgcn_mfma_f32_16x16x32_bf16(af[mi], bu[ni], accu[mi][ni], 0, 0, 0);
      }
  }
  // epilogue: SwiGLU, store h bf16
  int fb = ftile * 64 + wf * 32;
#pragma unroll
  for (int mi = 0; mi < 4; ++mi) {
#pragma unroll
    for (int i = 0; i < 4; ++i) {
      int ml = wm * 64 + mi * 16 + (lane >> 4) * 4 + i;
      int slot = mtile * 128 + ml;
      if (slot < cnt) {
#pragma unroll
        for (int ni = 0; ni < 2; ++ni) {
          float g = accg[mi][ni][i], u = accu[mi][ni][i];
          float hv = g / (1.f + __expf(-g)) * u;
          hbuf[(size_t)(base + slot) * FF + fb + ni * 16 + (lane & 15)] = f2bf(hv);
        }
      }
    }
  }
}

// ---------------- GEMM2: out += coef * (h W2), scatter via atomics ----------------
// tile 128M x 128N, BK=32; wave = 64x64; same XCD-chunked remap (512 blocks/expert)
__global__ __launch_bounds__(256) void gemm2_kernel(const unsigned short* __restrict__ hbuf,
                                                    const float* __restrict__ w2,
                                                    const int* __restrict__ tok,
                                                    const float* __restrict__ coef,
                                                    const int* __restrict__ rowptr,
                                                    float* __restrict__ out) {
  int f = blockIdx.x + 16 * blockIdx.y;
  int g = (f & 7) * 64 + (f >> 3);
  int ntile = g >> 5, mtile = g & 31;
  int e = blockIdx.z;
  int base = rowptr[e], cnt = rowptr[e + 1] - base;
  if (mtile * 128 >= cnt) return;
  __shared__ char As[128 * 64];
  __shared__ char Bs[128 * 64];
  __shared__ int tokL[128];
  __shared__ float cofL[128];
  int tid = threadIdx.x, lane = tid & 63, wave = tid >> 6;
  if (tid < 128) {
    int slot = min(mtile * 128 + tid, cnt - 1);
    tokL[tid] = tok[base + slot];
    cofL[tid] = coef[base + slot];
  }
  __syncthreads();   // tokL/cofL ready before any raw-barrier traffic

  int c = tid & 3, r0 = tid >> 2;
  int s0 = min(mtile * 128 + r0, cnt - 1);
  int s1 = min(mtile * 128 + 64 + r0, cnt - 1);
  const unsigned short* gA0 = hbuf + (size_t)(base + s0) * FF + c * 8;
  const unsigned short* gA1 = hbuf + (size_t)(base + s1) * FF + c * 8;
  int swzA = c ^ ((r0 >> 1) & 3);
  char* wA0 = As + r0 * 64 + (swzA << 4);
  char* wA1 = As + (64 + r0) * 64 + (swzA << 4);

  int bl = tid & 63, bw = tid >> 6;
  int n2 = bl * 2;
  int ncol = ntile * 128 + n2;
  const float* gB = w2 + ((size_t)e * FF + bw * 8) * HID + ncol;
  int swzB = bw ^ ((n2 >> 1) & 3);
  char* wB0 = Bs + n2 * 64 + (swzB << 4);
  char* wB1 = Bs + (n2 + 1) * 64 + (swzB << 4);

  int wm = wave >> 1, wn = wave & 1;
  int kc = lane >> 4;
  int aoff[4], bo[4];
#pragma unroll
  for (int mi = 0; mi < 4; ++mi) {
    int row = wm * 64 + mi * 16 + (lane & 15);
    aoff[mi] = row * 64 + ((kc ^ ((row >> 1) & 3)) << 4);
  }
#pragma unroll
  for (int ni = 0; ni < 4; ++ni) {
    int n = wn * 64 + ni * 16 + (lane & 15);
    bo[ni] = n * 64 + ((kc ^ ((n >> 1) & 3)) << 4);
  }

  const f32x4 vz = {0.f, 0.f, 0.f, 0.f};
  f32x4 acc[4][4];
#pragma unroll
  for (int mi = 0; mi < 4; ++mi)
#pragma unroll
    for (int ni = 0; ni < 4; ++ni) acc[mi][ni] = vz;

  short8 a0 = *(const short8*)gA0;
  short8 a1 = *(const short8*)gA1;
  float2 v[8];
#pragma unroll
  for (int dk = 0; dk < 8; ++dk) v[dk] = *(const float2*)(gB + (size_t)dk * HID);

  for (int k0 = 0; k0 < FF; k0 += 32) {
    int kn = (k0 + 32 < FF) ? k0 + 32 : k0;
    bar_top();
    u32x4 px, py;
#pragma unroll
    for (int j = 0; j < 4; ++j) {
      px[j] = cvt_pk(v[2 * j].x, v[2 * j + 1].x);
      py[j] = cvt_pk(v[2 * j].y, v[2 * j + 1].y);
    }
    *(short8*)wA0 = a0;
    *(short8*)wA1 = a1;
    *(u32x4*)wB0 = px;
    *(u32x4*)wB1 = py;
    a0 = *(const short8*)(gA0 + kn);
    a1 = *(const short8*)(gA1 + kn);
#pragma unroll
    for (int dk = 0; dk < 8; ++dk) v[dk] = *(const float2*)(gB + ((size_t)kn + dk) * HID);
    bar_lds_ready();
    short8 af[4], bb[4];
#pragma unroll
    for (int mi = 0; mi < 4; ++mi) af[mi] = *(const short8*)(As + aoff[mi]);
#pragma unroll
    for (int ni = 0; ni < 4; ++ni) bb[ni] = *(const short8*)(Bs + bo[ni]);
#pragma unroll
    for (int mi = 0; mi < 4; ++mi)
#pragma unroll
      for (int ni = 0; ni < 4; ++ni)
        acc[mi][ni] = __builtin_amdgcn_mfma_f32_16x16x32_bf16(af[mi], bb[ni], acc[mi][ni], 0, 0, 0);
  }
#pragma unroll
  for (int mi = 0; mi < 4; ++mi) {
#pragma unroll
    for (int i = 0; i < 4; ++i) {
      int ml = wm * 64 + mi * 16 + (lane >> 4) * 4 + i;
      int slot = mtile * 128 + ml;
      if (slot < cnt) {
        float cf = cofL[ml];
        float* op = out + (size_t)tokL[ml] * HID + ntile * 128 + wn * 64 + (lane & 15);
#pragma unroll
        for (int ni = 0; ni < 4; ++ni)
          unsafeAtomicAdd(op + ni * 16, cf * acc[mi][ni][i]);
      }
    }
  }
}

extern "C" void kernel_launch(void* const* d_in, const int* in_sizes, int n_in,
                              void* d_out, int out_size, void* d_ws, size_t ws_size,
                              hipStream_t stream) {
  const float* X  = (const float*)d_in[0];
  const float* RL = (const float*)d_in[1];
  const float* W1 = (const float*)d_in[2];
  const float* W2 = (const float*)d_in[3];
  float* out = (float*)d_out;

  const size_t OFF_EIDS = 4096;
  const size_t OFF_ECFS = 36864;
  const size_t OFF_TOK  = 69632;
  const size_t OFF_COEF = 102400;
  const size_t OFF_XB   = 135168;
  const size_t OFF_H    = 16912384;
  const size_t TOTAL    = 39981056;
  if (ws_size < TOTAL || n_in < 4) return;

  char* w = (char*)d_ws;
  int*    rowptr = (int*)w;
  int2*   eids   = (int2*)(w + OFF_EIDS);
  float2* ecfs   = (float2*)(w + OFF_ECFS);
  int*    tok    = (int*)(w + OFF_TOK);
  float*  coef   = (float*)(w + OFF_COEF);
  unsigned short* Xb   = (unsigned short*)(w + OFF_XB);
  unsigned short* hbuf = (unsigned short*)(w + OFF_H);

  hipMemsetAsync(d_out, 0, (size_t)T_TOK * HID * sizeof(float), stream);
  route_kernel<<<T_TOK / 256, 256, 0, stream>>>(RL, eids, ecfs);
  compact_kernel<<<NE, 256, 0, stream>>>(eids, ecfs, tok, coef, rowptr);
  cvtx_kernel<<<(T_TOK * HID / 4) / 256, 256, 0, stream>>>(X, Xb);
  gemm1_kernel<<<dim3(FF / 64, T_TOK / 128, NE), 256, 0, stream>>>(Xb, W1, tok, rowptr, hbuf);
  gemm2_kernel<<<dim3(HID / 128, T_TOK / 128, NE), 256, 0, stream>>>(hbuf, W2, tok, coef, rowptr, out);
}

// Round 4
// 377.549 us; speedup vs baseline: 1.1683x; 1.0847x over previous
//
#include <hip/hip_runtime.h>
#include <stdint.h>

#define T_TOK 4096
#define HID   2048
#define FF    1408
#define NE    8

typedef __attribute__((ext_vector_type(8))) short short8;
typedef __attribute__((ext_vector_type(4))) float f32x4;
typedef __attribute__((ext_vector_type(4))) unsigned int u32x4;

__device__ inline unsigned short f2bf(float f) {
  uint32_t u = __builtin_bit_cast(uint32_t, f);
  u += 0x7fffu + ((u >> 16) & 1u);   // RNE
  return (unsigned short)(u >> 16);
}

__device__ inline uint32_t cvt_pk(float a, float b) {
  uint32_t r;
  asm("v_cvt_pk_bf16_f32 %0, %1, %2" : "=v"(r) : "v"(a), "v"(b));
  return r;
}

// raw barrier pair: no compiler vmcnt(0) drain -> prefetch loads stay in flight
__device__ inline void bar_top() {
  asm volatile("" ::: "memory");
  __builtin_amdgcn_s_barrier();
  asm volatile("" ::: "memory");
}
__device__ inline void bar_lds_ready() {
  asm volatile("s_waitcnt lgkmcnt(0)" ::: "memory");
  __builtin_amdgcn_s_barrier();
  asm volatile("" ::: "memory");
}

// ---------------- router: per-token softmax + top2 ----------------
__global__ __launch_bounds__(256) void route_kernel(const float* __restrict__ logits,
                                                    int2* __restrict__ eids,
                                                    float2* __restrict__ ecfs) {
  int t = blockIdx.x * 256 + threadIdx.x;
  const float4* lp = (const float4*)(logits + (size_t)t * NE);
  float4 a = lp[0], b = lp[1];
  float l[8] = {a.x, a.y, a.z, a.w, b.x, b.y, b.z, b.w};
  float mx = l[0];
#pragma unroll
  for (int i = 1; i < 8; ++i) mx = fmaxf(mx, l[i]);
  float s = 0.f, p[8];
#pragma unroll
  for (int i = 0; i < 8; ++i) { p[i] = __expf(l[i] - mx); s += p[i]; }
  float inv = 1.f / s;
  int e0 = 0;
#pragma unroll
  for (int i = 1; i < 8; ++i) if (l[i] > l[e0]) e0 = i;
  int e1 = (e0 == 0) ? 1 : 0;
#pragma unroll
  for (int i = 0; i < 8; ++i) if (i != e0 && l[i] > l[e1]) e1 = i;
  eids[t] = make_int2(e0, e1);
  ecfs[t] = make_float2(p[e0] * inv, p[e1] * inv);
}

// ------------- deterministic per-expert compaction (8 blocks) -------------
__global__ __launch_bounds__(256) void compact_kernel(const int2* __restrict__ eids,
                                                      const float2* __restrict__ ecfs,
                                                      int* __restrict__ tok,
                                                      float* __restrict__ coef,
                                                      int* __restrict__ rowptr) {
  int e = blockIdx.x, tid = threadIdx.x;
  __shared__ int hist[8];
  __shared__ int wsum[4];
  __shared__ int runv;
  if (tid < 8) hist[tid] = 0;
  __syncthreads();
  for (int t = tid; t < T_TOK; t += 256) {
    int2 ei = eids[t];
    atomicAdd(&hist[ei.x], 1);
    atomicAdd(&hist[ei.y], 1);
  }
  __syncthreads();
  int off = 0;
  for (int j = 0; j < e; ++j) off += hist[j];
  if (tid == 0) {
    runv = 0;
    if (e == 0) rowptr[0] = 0;
    rowptr[e + 1] = off + hist[e];
  }
  __syncthreads();
  int wave = tid >> 6, lane = tid & 63;
  for (int c = 0; c < T_TOK; c += 256) {
    int t = c + tid;
    int2 ei = eids[t];
    float2 cf = ecfs[t];
    bool fl = false; float cv = 0.f;
    if (ei.x == e)      { fl = true; cv = cf.x; }
    else if (ei.y == e) { fl = true; cv = cf.y; }
    unsigned long long m = __ballot(fl);
    if (lane == 0) wsum[wave] = __popcll(m);
    __syncthreads();
    int woff = runv;
    for (int wv = 0; wv < wave; ++wv) woff += wsum[wv];
    int pos = off + woff + __popcll(m & ((1ull << lane) - 1ull));
    if (fl) { tok[pos] = t; coef[pos] = cv; }
    __syncthreads();
    if (tid == 0) runv += wsum[0] + wsum[1] + wsum[2] + wsum[3];
    __syncthreads();
  }
}

// ---------------- X f32 -> bf16 ----------------
__global__ __launch_bounds__(256) void cvtx_kernel(const float* __restrict__ x,
                                                   unsigned short* __restrict__ xb) {
  int i = blockIdx.x * 256 + threadIdx.x;  // 4 elems each
  float4 v = ((const float4*)x)[i];
  uint2 o;
  o.x = cvt_pk(v.x, v.y);
  o.y = cvt_pk(v.z, v.w);
  ((uint2*)xb)[i] = o;
}

// ------- weight convert+transpose: in[s][R][C] f32 -> out[s][C][R] bf16 -------
// 64x64 tile via LDS; both global sides coalesced. Row pad 72 -> 16B-aligned rows.
__global__ __launch_bounds__(256) void wcvt_kernel(const float* __restrict__ in,
                                                   unsigned short* __restrict__ out,
                                                   int R, int C) {
  __shared__ unsigned short t[64][72];
  const float* ip = in + ((size_t)blockIdx.z * R + blockIdx.y * 64) * C + blockIdx.x * 64;
  int tid = threadIdx.x;
  int r = tid >> 2, cg = (tid & 3) * 16;
  const float* rp = ip + (size_t)r * C + cg;
#pragma unroll
  for (int j = 0; j < 4; ++j) {
    float4 v = *(const float4*)(rp + j * 4);
    int c = cg + j * 4;
    t[c + 0][r] = f2bf(v.x);
    t[c + 1][r] = f2bf(v.y);
    t[c + 2][r] = f2bf(v.z);
    t[c + 3][r] = f2bf(v.w);
  }
  __syncthreads();
  int cr = tid >> 2, kg = (tid & 3) * 16;
  unsigned short* op = out + ((size_t)blockIdx.z * C + blockIdx.x * 64 + cr) * R +
                       blockIdx.y * 64 + kg;
  *(short8*)op = *(const short8*)&t[cr][kg];
  *(short8*)(op + 8) = *(const short8*)&t[cr][kg + 8];
}

// ======================= NEW PATH: bf16 pre-transposed weights =======================
// GEMM1: h = silu(X W1g) * (X W1u); tile 128M x (64f x {gate,up}); BK=32.
// B LDS row r: proj=(r>>4)&1, f_local=(r&15)+16*(r>>5)  -> SwiGLU is thread-local.
__global__ __launch_bounds__(256) void gemm1_kernel(const unsigned short* __restrict__ Xb,
                                                    const unsigned short* __restrict__ w1t,
                                                    const int* __restrict__ tok,
                                                    const int* __restrict__ rowptr,
                                                    unsigned short* __restrict__ hbuf) {
  int f = blockIdx.x + 22 * blockIdx.y;
  int g = (f & 7) * 88 + (f >> 3);          // XCD-chunked bijective remap (704 % 8 == 0)
  int ftile = g >> 5, mtile = g & 31;
  int e = blockIdx.z;
  int base = rowptr[e], cnt = rowptr[e + 1] - base;
  if (mtile * 128 >= cnt) return;
  __shared__ char As[128 * 64];
  __shared__ char Bs[128 * 64];
  int tid = threadIdx.x, lane = tid & 63, wave = tid >> 6;

  int c = tid & 3, r0 = tid >> 2;
  int s0 = min(mtile * 128 + r0, cnt - 1);
  int s1 = min(mtile * 128 + 64 + r0, cnt - 1);
  const unsigned short* gA0 = Xb + (size_t)tok[base + s0] * HID + c * 8;
  const unsigned short* gA1 = Xb + (size_t)tok[base + s1] * HID + c * 8;
  int swz = c ^ ((r0 >> 1) & 3);            // same for r0+64
  char* wA0 = As + r0 * 64 + (swz << 4);
  char* wA1 = As + (64 + r0) * 64 + (swz << 4);

  int proj = (r0 >> 4) & 1;
  int fl = (r0 & 15) + 16 * (r0 >> 5);
  const unsigned short* gB0 = w1t + ((size_t)(e * 2 + proj) * FF + ftile * 64 + fl) * HID + c * 8;
  const unsigned short* gB1 = gB0 + (size_t)32 * HID;   // row r0+64 -> f_local+32, same proj
  char* wB0 = Bs + r0 * 64 + (swz << 4);
  char* wB1 = Bs + (64 + r0) * 64 + (swz << 4);

  int wm = wave >> 1, wn = wave & 1, kc = lane >> 4;
  int aoff[4], boff[4];
#pragma unroll
  for (int mi = 0; mi < 4; ++mi) {
    int row = wm * 64 + mi * 16 + (lane & 15);
    aoff[mi] = row * 64 + ((kc ^ ((row >> 1) & 3)) << 4);
  }
#pragma unroll
  for (int ni = 0; ni < 4; ++ni) {
    int n = wn * 64 + ni * 16 + (lane & 15);
    boff[ni] = n * 64 + ((kc ^ ((n >> 1) & 3)) << 4);
  }

  const f32x4 vz = {0.f, 0.f, 0.f, 0.f};
  f32x4 acc[4][4];
#pragma unroll
  for (int mi = 0; mi < 4; ++mi)
#pragma unroll
    for (int ni = 0; ni < 4; ++ni) acc[mi][ni] = vz;

  short8 a0 = *(const short8*)gA0;
  short8 a1 = *(const short8*)gA1;
  short8 b0 = *(const short8*)gB0;
  short8 b1 = *(const short8*)gB1;

  for (int k0 = 0; k0 < HID; k0 += 32) {
    int kn = (k0 + 32 < HID) ? k0 + 32 : k0;
    bar_top();
    *(short8*)wA0 = a0;
    *(short8*)wA1 = a1;
    *(short8*)wB0 = b0;
    *(short8*)wB1 = b1;
    a0 = *(const short8*)(gA0 + kn);
    a1 = *(const short8*)(gA1 + kn);
    b0 = *(const short8*)(gB0 + kn);
    b1 = *(const short8*)(gB1 + kn);
    bar_lds_ready();
    short8 af[4], bb[4];
#pragma unroll
    for (int mi = 0; mi < 4; ++mi) af[mi] = *(const short8*)(As + aoff[mi]);
#pragma unroll
    for (int ni = 0; ni < 4; ++ni) bb[ni] = *(const short8*)(Bs + boff[ni]);
#pragma unroll
    for (int mi = 0; mi < 4; ++mi)
#pragma unroll
      for (int ni = 0; ni < 4; ++ni)
        acc[mi][ni] = __builtin_amdgcn_mfma_f32_16x16x32_bf16(af[mi], bb[ni], acc[mi][ni], 0, 0, 0);
  }
  // epilogue: SwiGLU thread-local (acc[mi][0,2]=gate, acc[mi][1,3]=up at f, f+16)
  int fb = ftile * 64 + wn * 32 + (lane & 15);
#pragma unroll
  for (int mi = 0; mi < 4; ++mi) {
#pragma unroll
    for (int i = 0; i < 4; ++i) {
      int ml = wm * 64 + mi * 16 + (lane >> 4) * 4 + i;
      int slot = mtile * 128 + ml;
      if (slot < cnt) {
        size_t hrow = (size_t)(base + slot) * FF + fb;
        float g0 = acc[mi][0][i], u0 = acc[mi][1][i];
        float g1 = acc[mi][2][i], u1 = acc[mi][3][i];
        hbuf[hrow]      = f2bf(g0 / (1.f + __expf(-g0)) * u0);
        hbuf[hrow + 16] = f2bf(g1 / (1.f + __expf(-g1)) * u1);
      }
    }
  }
}

// GEMM2: out += coef * (h W2); tile 128M x 128N; BK=32; B = w2t[e][h][f] bf16.
__global__ __launch_bounds__(256) void gemm2_kernel(const unsigned short* __restrict__ hbuf,
                                                    const unsigned short* __restrict__ w2t,
                                                    const int* __restrict__ tok,
                                                    const float* __restrict__ coef,
                                                    const int* __restrict__ rowptr,
                                                    float* __restrict__ out) {
  int f = blockIdx.x + 16 * blockIdx.y;
  int g = (f & 7) * 64 + (f >> 3);
  int ntile = g >> 5, mtile = g & 31;
  int e = blockIdx.z;
  int base = rowptr[e], cnt = rowptr[e + 1] - base;
  if (mtile * 128 >= cnt) return;
  __shared__ char As[128 * 64];
  __shared__ char Bs[128 * 64];
  __shared__ int tokL[128];
  __shared__ float cofL[128];
  int tid = threadIdx.x, lane = tid & 63, wave = tid >> 6;
  if (tid < 128) {
    int slot = min(mtile * 128 + tid, cnt - 1);
    tokL[tid] = tok[base + slot];
    cofL[tid] = coef[base + slot];
  }
  __syncthreads();

  int c = tid & 3, r0 = tid >> 2;
  int s0 = min(mtile * 128 + r0, cnt - 1);
  int s1 = min(mtile * 128 + 64 + r0, cnt - 1);
  const unsigned short* gA0 = hbuf + (size_t)(base + s0) * FF + c * 8;
  const unsigned short* gA1 = hbuf + (size_t)(base + s1) * FF + c * 8;
  int swz = c ^ ((r0 >> 1) & 3);
  char* wA0 = As + r0 * 64 + (swz << 4);
  char* wA1 = As + (64 + r0) * 64 + (swz << 4);

  const unsigned short* gB0 = w2t + ((size_t)e * HID + ntile * 128 + r0) * FF + c * 8;
  const unsigned short* gB1 = gB0 + (size_t)64 * FF;
  char* wB0 = Bs + r0 * 64 + (swz << 4);
  char* wB1 = Bs + (64 + r0) * 64 + (swz << 4);

  int wm = wave >> 1, wn = wave & 1, kc = lane >> 4;
  int aoff[4], boff[4];
#pragma unroll
  for (int mi = 0; mi < 4; ++mi) {
    int row = wm * 64 + mi * 16 + (lane & 15);
    aoff[mi] = row * 64 + ((kc ^ ((row >> 1) & 3)) << 4);
  }
#pragma unroll
  for (int ni = 0; ni < 4; ++ni) {
    int n = wn * 64 + ni * 16 + (lane & 15);
    boff[ni] = n * 64 + ((kc ^ ((n >> 1) & 3)) << 4);
  }

  const f32x4 vz = {0.f, 0.f, 0.f, 0.f};
  f32x4 acc[4][4];
#pragma unroll
  for (int mi = 0; mi < 4; ++mi)
#pragma unroll
    for (int ni = 0; ni < 4; ++ni) acc[mi][ni] = vz;

  short8 a0 = *(const short8*)gA0;
  short8 a1 = *(const short8*)gA1;
  short8 b0 = *(const short8*)gB0;
  short8 b1 = *(const short8*)gB1;

  for (int k0 = 0; k0 < FF; k0 += 32) {
    int kn = (k0 + 32 < FF) ? k0 + 32 : k0;
    bar_top();
    *(short8*)wA0 = a0;
    *(short8*)wA1 = a1;
    *(short8*)wB0 = b0;
    *(short8*)wB1 = b1;
    a0 = *(const short8*)(gA0 + kn);
    a1 = *(const short8*)(gA1 + kn);
    b0 = *(const short8*)(gB0 + kn);
    b1 = *(const short8*)(gB1 + kn);
    bar_lds_ready();
    short8 af[4], bb[4];
#pragma unroll
    for (int mi = 0; mi < 4; ++mi) af[mi] = *(const short8*)(As + aoff[mi]);
#pragma unroll
    for (int ni = 0; ni < 4; ++ni) bb[ni] = *(const short8*)(Bs + boff[ni]);
#pragma unroll
    for (int mi = 0; mi < 4; ++mi)
#pragma unroll
      for (int ni = 0; ni < 4; ++ni)
        acc[mi][ni] = __builtin_amdgcn_mfma_f32_16x16x32_bf16(af[mi], bb[ni], acc[mi][ni], 0, 0, 0);
  }
#pragma unroll
  for (int mi = 0; mi < 4; ++mi) {
#pragma unroll
    for (int i = 0; i < 4; ++i) {
      int ml = wm * 64 + mi * 16 + (lane >> 4) * 4 + i;
      int slot = mtile * 128 + ml;
      if (slot < cnt) {
        float cf = cofL[ml];
        float* op = out + (size_t)tokL[ml] * HID + ntile * 128 + wn * 64 + (lane & 15);
#pragma unroll
        for (int ni = 0; ni < 4; ++ni)
          unsafeAtomicAdd(op + ni * 16, cf * acc[mi][ni][i]);
      }
    }
  }
}

// ======================= LEGACY PATH (round-3, f32 weights) =======================
__global__ __launch_bounds__(256) void gemm1_legacy(const unsigned short* __restrict__ Xb,
                                                    const float* __restrict__ w1,
                                                    const int* __restrict__ tok,
                                                    const int* __restrict__ rowptr,
                                                    unsigned short* __restrict__ hbuf) {
  int f = blockIdx.x + 22 * blockIdx.y;
  int g = (f & 7) * 88 + (f >> 3);
  int ftile = g >> 5, mtile = g & 31;
  int e = blockIdx.z;
  int base = rowptr[e], cnt = rowptr[e + 1] - base;
  if (mtile * 128 >= cnt) return;
  __shared__ char As[128 * 64];
  __shared__ char Bs[128 * 64];
  int tid = threadIdx.x, lane = tid & 63, wave = tid >> 6;
  int c = tid & 3, r0 = tid >> 2;
  int s0 = min(mtile * 128 + r0, cnt - 1);
  int s1 = min(mtile * 128 + 64 + r0, cnt - 1);
  const unsigned short* gA0 = Xb + (size_t)tok[base + s0] * HID + c * 8;
  const unsigned short* gA1 = Xb + (size_t)tok[base + s1] * HID + c * 8;
  int swzA = c ^ ((r0 >> 1) & 3);
  char* wA0 = As + r0 * 64 + (swzA << 4);
  char* wA1 = As + (64 + r0) * 64 + (swzA << 4);
  int bl = tid & 63, bw = tid >> 6;
  int n2 = bl * 2;
  int gsel = (n2 >= 64) ? 1 : 0;
  int fcol = ftile * 64 + (n2 & 63);
  const float* gB = w1 + ((size_t)(e * 2 + gsel) * HID + bw * 8) * FF + fcol;
  int swzB = bw ^ ((n2 >> 1) & 3);
  char* wB0 = Bs + n2 * 64 + (swzB << 4);
  char* wB1 = Bs + (n2 + 1) * 64 + (swzB << 4);
  int wm = wave >> 1, wf = wave & 1;
  int kc = lane >> 4;
  int aoff[4];
#pragma unroll
  for (int mi = 0; mi < 4; ++mi) {
    int row = wm * 64 + mi * 16 + (lane & 15);
    aoff[mi] = row * 64 + ((kc ^ ((row >> 1) & 3)) << 4);
  }
  int bgo[2];
#pragma unroll
  for (int ni = 0; ni < 2; ++ni) {
    int ng = wf * 32 + ni * 16 + (lane & 15);
    bgo[ni] = ng * 64 + ((kc ^ ((ng >> 1) & 3)) << 4);
  }
  const f32x4 vz = {0.f, 0.f, 0.f, 0.f};
  f32x4 accg[4][2], accu[4][2];
#pragma unroll
  for (int mi = 0; mi < 4; ++mi)
#pragma unroll
    for (int ni = 0; ni < 2; ++ni) { accg[mi][ni] = vz; accu[mi][ni] = vz; }
  short8 a0 = *(const short8*)gA0;
  short8 a1 = *(const short8*)gA1;
  float2 v[8];
#pragma unroll
  for (int dk = 0; dk < 8; ++dk) v[dk] = *(const float2*)(gB + (size_t)dk * FF);
  for (int k0 = 0; k0 < HID; k0 += 32) {
    int kn = (k0 + 32 < HID) ? k0 + 32 : k0;
    bar_top();
    u32x4 px, py;
#pragma unroll
    for (int j = 0; j < 4; ++j) {
      px[j] = cvt_pk(v[2 * j].x, v[2 * j + 1].x);
      py[j] = cvt_pk(v[2 * j].y, v[2 * j + 1].y);
    }
    *(short8*)wA0 = a0;
    *(short8*)wA1 = a1;
    *(u32x4*)wB0 = px;
    *(u32x4*)wB1 = py;
    a0 = *(const short8*)(gA0 + kn);
    a1 = *(const short8*)(gA1 + kn);
#pragma unroll
    for (int dk = 0; dk < 8; ++dk) v[dk] = *(const float2*)(gB + ((size_t)kn + dk) * FF);
    bar_lds_ready();
    short8 af[4];
#pragma unroll
    for (int mi = 0; mi < 4; ++mi) af[mi] = *(const short8*)(As + aoff[mi]);
    short8 bg[2], bu[2];
#pragma unroll
    for (int ni = 0; ni < 2; ++ni) {
      bg[ni] = *(const short8*)(Bs + bgo[ni]);
      bu[ni] = *(const short8*)(Bs + bgo[ni] + 64 * 64);
    }
#pragma unroll
    for (int mi = 0; mi < 4; ++mi)
#pragma unroll
      for (int ni = 0; ni < 2; ++ni) {
        accg[mi][ni] = __builtin_amdgcn_mfma_f32_16x16x32_bf16(af[mi], bg[ni], accg[mi][ni], 0, 0, 0);
        accu[mi][ni] = __builtin_amdgcn_mfma_f32_16x16x32_bf16(af[mi], bu[ni], accu[mi][ni], 0, 0, 0);
      }
  }
  int fb = ftile * 64 + wf * 32;
#pragma unroll
  for (int mi = 0; mi < 4; ++mi) {
#pragma unroll
    for (int i = 0; i < 4; ++i) {
      int ml = wm * 64 + mi * 16 + (lane >> 4) * 4 + i;
      int slot = mtile * 128 + ml;
      if (slot < cnt) {
#pragma unroll
        for (int ni = 0; ni < 2; ++ni) {
          float gg = accg[mi][ni][i], uu = accu[mi][ni][i];
          float hv = gg / (1.f + __expf(-gg)) * uu;
          hbuf[(size_t)(base + slot) * FF + fb + ni * 16 + (lane & 15)] = f2bf(hv);
        }
      }
    }
  }
}

__global__ __launch_bounds__(256) void gemm2_legacy(const unsigned short* __restrict__ hbuf,
                                                    const float* __restrict__ w2,
                                                    const int* __restrict__ tok,
                                                    const float* __restrict__ coef,
                                                    const int* __restrict__ rowptr,
                                                    float* __restrict__ out) {
  int f = blockIdx.x + 16 * blockIdx.y;
  int g = (f & 7) * 64 + (f >> 3);
  int ntile = g >> 5, mtile = g & 31;
  int e = blockIdx.z;
  int base = rowptr[e], cnt = rowptr[e + 1] - base;
  if (mtile * 128 >= cnt) return;
  __shared__ char As[128 * 64];
  __shared__ char Bs[128 * 64];
  __shared__ int tokL[128];
  __shared__ float cofL[128];
  int tid = threadIdx.x, lane = tid & 63, wave = tid >> 6;
  if (tid < 128) {
    int slot = min(mtile * 128 + tid, cnt - 1);
    tokL[tid] = tok[base + slot];
    cofL[tid] = coef[base + slot];
  }
  __syncthreads();
  int c = tid & 3, r0 = tid >> 2;
  int s0 = min(mtile * 128 + r0, cnt - 1);
  int s1 = min(mtile * 128 + 64 + r0, cnt - 1);
  const unsigned short* gA0 = hbuf + (size_t)(base + s0) * FF + c * 8;
  const unsigned short* gA1 = hbuf + (size_t)(base + s1) * FF + c * 8;
  int swzA = c ^ ((r0 >> 1) & 3);
  char* wA0 = As + r0 * 64 + (swzA << 4);
  char* wA1 = As + (64 + r0) * 64 + (swzA << 4);
  int bl = tid & 63, bw = tid >> 6;
  int n2 = bl * 2;
  int ncol = ntile * 128 + n2;
  const float* gB = w2 + ((size_t)e * FF + bw * 8) * HID + ncol;
  int swzB = bw ^ ((n2 >> 1) & 3);
  char* wB0 = Bs + n2 * 64 + (swzB << 4);
  char* wB1 = Bs + (n2 + 1) * 64 + (swzB << 4);
  int wm = wave >> 1, wn = wave & 1;
  int kc = lane >> 4;
  int aoff[4], bo[4];
#pragma unroll
  for (int mi = 0; mi < 4; ++mi) {
    int row = wm * 64 + mi * 16 + (lane & 15);
    aoff[mi] = row * 64 + ((kc ^ ((row >> 1) & 3)) << 4);
  }
#pragma unroll
  for (int ni = 0; ni < 4; ++ni) {
    int n = wn * 64 + ni * 16 + (lane & 15);
    bo[ni] = n * 64 + ((kc ^ ((n >> 1) & 3)) << 4);
  }
  const f32x4 vz = {0.f, 0.f, 0.f, 0.f};
  f32x4 acc[4][4];
#pragma unroll
  for (int mi = 0; mi < 4; ++mi)
#pragma unroll
    for (int ni = 0; ni < 4; ++ni) acc[mi][ni] = vz;
  short8 a0 = *(const short8*)gA0;
  short8 a1 = *(const short8*)gA1;
  float2 v[8];
#pragma unroll
  for (int dk = 0; dk < 8; ++dk) v[dk] = *(const float2*)(gB + (size_t)dk * HID);
  for (int k0 = 0; k0 < FF; k0 += 32) {
    int kn = (k0 + 32 < FF) ? k0 + 32 : k0;
    bar_top();
    u32x4 px, py;
#pragma unroll
    for (int j = 0; j < 4; ++j) {
      px[j] = cvt_pk(v[2 * j].x, v[2 * j + 1].x);
      py[j] = cvt_pk(v[2 * j].y, v[2 * j + 1].y);
    }
    *(short8*)wA0 = a0;
    *(short8*)wA1 = a1;
    *(u32x4*)wB0 = px;
    *(u32x4*)wB1 = py;
    a0 = *(const short8*)(gA0 + kn);
    a1 = *(const short8*)(gA1 + kn);
#pragma unroll
    for (int dk = 0; dk < 8; ++dk) v[dk] = *(const float2*)(gB + ((size_t)kn + dk) * HID);
    bar_lds_ready();
    short8 af[4], bb[4];
#pragma unroll
    for (int mi = 0; mi < 4; ++mi) af[mi] = *(const short8*)(As + aoff[mi]);
#pragma unroll
    for (int ni = 0; ni < 4; ++ni) bb[ni] = *(const short8*)(Bs + bo[ni]);
#pragma unroll
    for (int mi = 0; mi < 4; ++mi)
#pragma unroll
      for (int ni = 0; ni < 4; ++ni)
        acc[mi][ni] = __builtin_amdgcn_mfma_f32_16x16x32_bf16(af[mi], bb[ni], acc[mi][ni], 0, 0, 0);
  }
#pragma unroll
  for (int mi = 0; mi < 4; ++mi) {
#pragma unroll
    for (int i = 0; i < 4; ++i) {
      int ml = wm * 64 + mi * 16 + (lane >> 4) * 4 + i;
      int slot = mtile * 128 + ml;
      if (slot < cnt) {
        float cf = cofL[ml];
        float* op = out + (size_t)tokL[ml] * HID + ntile * 128 + wn * 64 + (lane & 15);
#pragma unroll
        for (int ni = 0; ni < 4; ++ni)
          unsafeAtomicAdd(op + ni * 16, cf * acc[mi][ni][i]);
      }
    }
  }
}

extern "C" void kernel_launch(void* const* d_in, const int* in_sizes, int n_in,
                              void* d_out, int out_size, void* d_ws, size_t ws_size,
                              hipStream_t stream) {
  const float* X  = (const float*)d_in[0];
  const float* RL = (const float*)d_in[1];
  const float* W1 = (const float*)d_in[2];
  const float* W2 = (const float*)d_in[3];
  float* out = (float*)d_out;

  const size_t OFF_EIDS = 4096;
  const size_t OFF_ECFS = 36864;
  const size_t OFF_TOK  = 69632;
  const size_t OFF_COEF = 102400;
  const size_t OFF_XB   = 135168;
  const size_t OFF_H    = 16912384;
  const size_t OFF_W1T  = 39981056;                    // 16*1408*2048*2 = 92274688
  const size_t OFF_W2T  = 132255744;                   // 8*2048*1408*2 = 46137344
  const size_t TOTAL1   = 39981056;
  const size_t TOTAL2   = 178393088;
  if (ws_size < TOTAL1 || n_in < 4) return;

  char* w = (char*)d_ws;
  int*    rowptr = (int*)w;
  int2*   eids   = (int2*)(w + OFF_EIDS);
  float2* ecfs   = (float2*)(w + OFF_ECFS);
  int*    tok    = (int*)(w + OFF_TOK);
  float*  coef   = (float*)(w + OFF_COEF);
  unsigned short* Xb   = (unsigned short*)(w + OFF_XB);
  unsigned short* hbuf = (unsigned short*)(w + OFF_H);

  hipMemsetAsync(d_out, 0, (size_t)T_TOK * HID * sizeof(float), stream);
  route_kernel<<<T_TOK / 256, 256, 0, stream>>>(RL, eids, ecfs);
  compact_kernel<<<NE, 256, 0, stream>>>(eids, ecfs, tok, coef, rowptr);
  cvtx_kernel<<<(T_TOK * HID / 4) / 256, 256, 0, stream>>>(X, Xb);

  if (ws_size >= TOTAL2) {
    unsigned short* w1t = (unsigned short*)(w + OFF_W1T);
    unsigned short* w2t = (unsigned short*)(w + OFF_W2T);
    // w1[e*2+g][k=2048][f=1408] -> w1t[e*2+g][f][k]
    wcvt_kernel<<<dim3(FF / 64, HID / 64, NE * 2), 256, 0, stream>>>(W1, w1t, HID, FF);
    // w2[e][f=1408][h=2048] -> w2t[e][h][f]
    wcvt_kernel<<<dim3(HID / 64, FF / 64, NE), 256, 0, stream>>>(W2, w2t, FF, HID);
    gemm1_kernel<<<dim3(FF / 64, T_TOK / 128, NE), 256, 0, stream>>>(Xb, w1t, tok, rowptr, hbuf);
    gemm2_kernel<<<dim3(HID / 128, T_TOK / 128, NE), 256, 0, stream>>>(hbuf, w2t, tok, coef, rowptr, out);
  } else {
    gemm1_legacy<<<dim3(FF / 64, T_TOK / 128, NE), 256, 0, stream>>>(Xb, W1, tok, rowptr, hbuf);
    gemm2_legacy<<<dim3(HID / 128, T_TOK / 128, NE), 256, 0, stream>>>(hbuf, W2, tok, coef, rowptr, out);
  }
}